// Round 4
// baseline (168.338 us; speedup 1.0000x reference)
//
#include <hip/hip_runtime.h>

// Cubic B-spline prefilter (Unser), periodic, axes 2,3,4 of (2,3,160,160,160) fp32.
//
// Kernel A (pass_d2): axis-2 (stride 160*160). 4 threads/line, 40-output chunks,
//   16-step truncated warm-up (z^16 ~ 7e-10, threshold 0.71). ~20 waves/CU.
// Kernel B (pass_d3d4): axes 3+4 fused. One 640-thread block stages a contiguous
//   (d3,d4) plane (102.4 KB) in LDS, filters both axes, stores once.
//   v2 fixes vs R2: (a) per-thread state is f[40] (no spill -> no 2x scratch
//   writes): anticausal warm-up c+ values are read from the NEIGHBOR chunk's
//   LDS rows instead of being carried in registers; (b) all-scalar load/store
//   with r=4k+tid/160, c=tid%160 -> contiguous 256B global spans per wave and
//   2-way (free) LDS banks everywhere.

#define NAX   160
#define PLN   25600      // 160*160
#define VOL   4096000    // 160*PLN
#define ZP    (-0.26794919243112270647f)   // sqrt(3)-2
#define KW    16         // warm-up length

// ---------------- Kernel A: axis-2, chunked register IIR --------------------
__global__ __launch_bounds__(256, 5)
void pass_d2(const float* __restrict__ in, float* __restrict__ out)
{
    const float z = ZP;
    const int l     = threadIdx.x & 63;          // lane -> line (coalesced)
    const int chunk = threadIdx.x >> 6;          // wave -> chunk 0..3
    const int L = blockIdx.x * 64 + l;           // line id 0..153599
    const int v = L / PLN;                       // (b,c) volume 0..5
    const int i = L - v * PLN;                   // offset within plane
    const float* src = in  + (size_t)v * VOL + i;
    float*       dst = out + (size_t)v * VOL + i;
    const int n0 = chunk * 40;

    // causal c+(n) = 6 x(n) + z c+(n-1), warm-up from n0-16 (periodic wrap)
    float st = 0.0f;
    #pragma unroll
    for (int s = 0; s < KW; ++s) {
        int r = n0 - KW + s; if (r < 0) r += NAX;
        st = fmaf(z, st, 6.0f * src[(size_t)r * PLN]);
    }
    float cp[56];                                // c+ for rows n0..n0+55
    #pragma unroll
    for (int s = 0; s < 56; ++s) {
        int r = n0 + s; if (r >= NAX) r -= NAX;
        st = fmaf(z, st, 6.0f * src[(size_t)r * PLN]);
        cp[s] = st;
    }
    // anticausal c-(n) = z (c-(n+1) - c+(n)): 16 warm steps, then 40 outputs
    float sm = 0.0f;
    #pragma unroll
    for (int s = 55; s >= 40; --s) sm = z * (sm - cp[s]);
    #pragma unroll
    for (int s = 39; s >= 0; --s) {
        sm = z * (sm - cp[s]);
        dst[(size_t)(n0 + s) * PLN] = sm;
    }
}

// ---------------- Kernel B: fused axes 3+4, plane in LDS --------------------
__device__ __forceinline__ int swz(int r, int c) {
    return r * NAX + (c ^ (r & 31));
}

__global__ __launch_bounds__(640, 2)
void pass_d3d4(float* __restrict__ buf)
{
    __shared__ float P[PLN];                     // 102.4 KB -> 1 block/CU
    const float z = ZP;
    const int tid = threadIdx.x;                 // 0..639
    float* plane = buf + (size_t)blockIdx.x * PLN;

    const int c  = tid % NAX;                    // column (d3) / row (d4)
    const int tq = tid / NAX;                    // chunk 0..3
    const int n0 = tq * 40;

    // ---- load: element (r=4k+tq, c). Wave = contiguous 256B global span;
    //      LDS banks (c^(r&31)) 2-way free.
    #pragma unroll
    for (int k = 0; k < 40; ++k) {
        const int r = 4 * k + tq;
        P[swz(r, c)] = plane[r * NAX + c];
    }
    __syncthreads();

    float f[40];

    // ---- axis d3: rows vary, fixed column c; this thread owns rows n0..n0+39
    {
        // causal with 16-row warm-up (periodic wrap)
        float st = 0.0f;
        #pragma unroll
        for (int s = 0; s < KW; ++s) {
            int r = n0 - KW + s; if (r < 0) r += NAX;
            st = fmaf(z, st, 6.0f * P[swz(r, c)]);
        }
        #pragma unroll
        for (int s = 0; s < 40; ++s) {
            st = fmaf(z, st, 6.0f * P[swz(n0 + s, c)]);
            f[s] = st;
        }
        __syncthreads();                 // all x-reads done
        #pragma unroll
        for (int s = 0; s < 40; ++s)     // publish c+ over x
            P[swz(n0 + s, c)] = f[s];
        __syncthreads();                 // c+ visible
        // anticausal warm-up from neighbor chunk's c+ (rows n0+40..n0+55, wraps)
        float sm = 0.0f;
        #pragma unroll
        for (int s = KW - 1; s >= 0; --s) {
            int r = n0 + 40 + s; if (r >= NAX) r -= NAX;
            sm = z * (sm - P[swz(r, c)]);
        }
        __syncthreads();                 // all warm c+ reads done
        #pragma unroll
        for (int s = 39; s >= 0; --s) {  // outputs over own rows
            sm = z * (sm - f[s]);
            P[swz(n0 + s, c)] = sm;
        }
        __syncthreads();
    }

    // ---- axis d4: columns vary, fixed row rr=c; this thread owns cols n0..n0+39
    {
        const int rr = c;
        float st = 0.0f;
        #pragma unroll
        for (int s = 0; s < KW; ++s) {
            int cc = n0 - KW + s; if (cc < 0) cc += NAX;
            st = fmaf(z, st, 6.0f * P[swz(rr, cc)]);
        }
        #pragma unroll
        for (int s = 0; s < 40; ++s) {
            st = fmaf(z, st, 6.0f * P[swz(rr, n0 + s)]);
            f[s] = st;
        }
        __syncthreads();
        #pragma unroll
        for (int s = 0; s < 40; ++s)
            P[swz(rr, n0 + s)] = f[s];
        __syncthreads();
        float sm = 0.0f;
        #pragma unroll
        for (int s = KW - 1; s >= 0; --s) {
            int cc = n0 + 40 + s; if (cc >= NAX) cc -= NAX;
            sm = z * (sm - P[swz(rr, cc)]);
        }
        __syncthreads();
        #pragma unroll
        for (int s = 39; s >= 0; --s) {
            sm = z * (sm - f[s]);
            P[swz(rr, n0 + s)] = sm;
        }
        __syncthreads();
    }

    // ---- store (mirror of load) ----
    #pragma unroll
    for (int k = 0; k < 40; ++k) {
        const int r = 4 * k + tq;
        plane[r * NAX + c] = P[swz(r, c)];
    }
}

extern "C" void kernel_launch(void* const* d_in, const int* in_sizes, int n_in,
                              void* d_out, int out_size, void* d_ws, size_t ws_size,
                              hipStream_t stream) {
    (void)in_sizes; (void)n_in; (void)d_ws; (void)ws_size; (void)out_size;
    const float* x = (const float*)d_in[0];
    float* out = (float*)d_out;

    // axis-2 pass: 153600 lines, 64 lines x 4 chunks per 256-thread block
    pass_d2<<<2400, 256, 0, stream>>>(x, out);
    // fused axes 3+4: one block per contiguous (d3,d4) plane, in-place on out
    pass_d3d4<<<960, 640, 0, stream>>>(out);
}

// Round 5
// 93.787 us; speedup vs baseline: 1.7949x; 1.7949x over previous
//
#include <hip/hip_runtime.h>

// Cubic B-spline prefilter (Unser), periodic, axes 2,3,4 of (2,3,160,160,160) fp32.
//
// Pipeline (primary, uses d_ws as intermediate):
//   pass_d2   : axis-2 IIR (stride 160^2), register-chunked, in -> ws
//   slab_d3d4 : axes 3+4 fused. 320-thread block owns a 40x160 slab of one
//               (d3,d4) plane. d3 sweep streams GLOBAL reads into registers
//               (16-warm + 20 out + 16 tail), publishes slab to 25.6 KB LDS,
//               d4 sweep reads LDS into registers, coalesced store. 3 barriers,
//               ~55 VGPR, 6 blocks/CU (30 waves, 94% occupancy). ws -> out.
// Fallback (ws too small): R3-validated in-place full-plane kernel.

#define NAX   160
#define PLN   25600      // 160*160
#define VOL   4096000    // 160*PLN
#define ZP    (-0.26794919243112270647f)   // sqrt(3)-2
#define KW    16         // truncated warm-up (z^16 ~ 7.4e-10)

// ---------------- Kernel A: axis-2, chunked register IIR --------------------
__global__ __launch_bounds__(256, 5)
void pass_d2(const float* __restrict__ in, float* __restrict__ out)
{
    const float z = ZP;
    const int l     = threadIdx.x & 63;
    const int chunk = threadIdx.x >> 6;
    const int L = blockIdx.x * 64 + l;
    const int v = L / PLN;
    const int i = L - v * PLN;
    const float* src = in  + (size_t)v * VOL + i;
    float*       dst = out + (size_t)v * VOL + i;
    const int n0 = chunk * 40;

    float st = 0.0f;
    #pragma unroll
    for (int s = 0; s < KW; ++s) {
        int r = n0 - KW + s; if (r < 0) r += NAX;
        st = fmaf(z, st, 6.0f * src[(size_t)r * PLN]);
    }
    float cp[56];
    #pragma unroll
    for (int s = 0; s < 56; ++s) {
        int r = n0 + s; if (r >= NAX) r -= NAX;
        st = fmaf(z, st, 6.0f * src[(size_t)r * PLN]);
        cp[s] = st;
    }
    float sm = 0.0f;
    #pragma unroll
    for (int s = 55; s >= 40; --s) sm = z * (sm - cp[s]);
    #pragma unroll
    for (int s = 39; s >= 0; --s) {
        sm = z * (sm - cp[s]);
        dst[(size_t)(n0 + s) * PLN] = sm;
    }
}

// ---------------- Kernel B: fused axes 3+4, 40-row slab ---------------------
__device__ __forceinline__ int swz(int r, int c) {
    return r * NAX + (c ^ (r & 31));
}

__global__ __launch_bounds__(320, 6)
void slab_d3d4(const float* __restrict__ src, float* __restrict__ dst)
{
    __shared__ float Y[40 * NAX];        // 25.6 KB exchange buffer
    const float z = ZP;
    const int tid = threadIdx.x;         // 0..319
    const int p  = blockIdx.x >> 2;      // plane 0..959
    const int q  = blockIdx.x & 3;       // slab 0..3
    const int R0 = 40 * q;               // first output d3-row of slab
    const float* pin  = src + (size_t)p * PLN;
    float*       pout = dst + (size_t)p * PLN;

    float f[20];

    // ---- d3: thread (c, h) -> rows R0+20h .. R0+20h+19, column c -----------
    // reads x directly from global (coalesced: lane -> consecutive c)
    {
        const int c  = tid % NAX;
        const int h  = tid / NAX;        // 0..1
        const int n0 = R0 + 20 * h;      // <= 140, so n0..n0+19 never wraps
        float st = 0.0f;
        #pragma unroll
        for (int s = 0; s < KW; ++s) {   // causal warm-up
            int r = n0 - KW + s; if (r < 0) r += NAX;
            st = fmaf(z, st, 6.0f * pin[r * NAX + c]);
        }
        #pragma unroll
        for (int s = 0; s < 20; ++s) {   // causal outputs
            st = fmaf(z, st, 6.0f * pin[(n0 + s) * NAX + c]);
            f[s] = st;
        }
        float cpe[KW];                   // c+ tail for anticausal warm-up
        #pragma unroll
        for (int s = 0; s < KW; ++s) {
            int r = n0 + 20 + s; if (r >= NAX) r -= NAX;
            st = fmaf(z, st, 6.0f * pin[r * NAX + c]);
            cpe[s] = st;
        }
        float sm = 0.0f;
        #pragma unroll
        for (int s = KW - 1; s >= 0; --s) sm = z * (sm - cpe[s]);
        #pragma unroll
        for (int s = 19; s >= 0; --s) { sm = z * (sm - f[s]); f[s] = sm; }

        const int lr0 = 20 * h;          // publish slab rows (local 0..39)
        #pragma unroll
        for (int s = 0; s < 20; ++s)
            Y[swz(lr0 + s, c)] = f[s];
    }
    __syncthreads();

    // ---- d4: thread (rr, mq) -> slab row rr, columns 20mq .. 20mq+19 -------
    {
        const int rr = tid % 40;
        const int mq = tid / 40;         // 0..7
        const int m0 = 20 * mq;
        float st = 0.0f;
        #pragma unroll
        for (int s = 0; s < KW; ++s) {
            int cc = m0 - KW + s; if (cc < 0) cc += NAX;
            st = fmaf(z, st, 6.0f * Y[swz(rr, cc)]);
        }
        #pragma unroll
        for (int s = 0; s < 20; ++s) {
            st = fmaf(z, st, 6.0f * Y[swz(rr, m0 + s)]);
            f[s] = st;
        }
        float cpe[KW];
        #pragma unroll
        for (int s = 0; s < KW; ++s) {
            int cc = m0 + 20 + s; if (cc >= NAX) cc -= NAX;
            st = fmaf(z, st, 6.0f * Y[swz(rr, cc)]);
            cpe[s] = st;
        }
        float sm = 0.0f;
        #pragma unroll
        for (int s = KW - 1; s >= 0; --s) sm = z * (sm - cpe[s]);
        #pragma unroll
        for (int s = 19; s >= 0; --s) { sm = z * (sm - f[s]); f[s] = sm; }

        __syncthreads();                 // all Y reads done before overwrite
        #pragma unroll
        for (int s = 0; s < 20; ++s)
            Y[swz(rr, m0 + s)] = f[s];
    }
    __syncthreads();

    // ---- coalesced store of the slab --------------------------------------
    #pragma unroll
    for (int k = 0; k < 20; ++k) {
        const int idx = tid + 320 * k;   // 0..6399
        const int lr  = idx / NAX;
        const int c   = idx - lr * NAX;
        pout[(R0 + lr) * NAX + c] = Y[swz(lr, c)];
    }
}

// ---------------- Fallback: R3-validated in-place full-plane kernel ---------
__global__ __launch_bounds__(640, 2)
void pass_d3d4(float* __restrict__ buf)
{
    __shared__ float P[PLN];
    const float z = ZP;
    const int tid = threadIdx.x;
    float* plane = buf + (size_t)blockIdx.x * PLN;

    const int c  = tid % NAX;
    const int tq = tid / NAX;
    const int n0 = tq * 40;

    #pragma unroll
    for (int k = 0; k < 40; ++k) {
        const int r = 4 * k + tq;
        P[swz(r, c)] = plane[r * NAX + c];
    }
    __syncthreads();

    float f[40];
    {
        float st = 0.0f;
        #pragma unroll
        for (int s = 0; s < KW; ++s) {
            int r = n0 - KW + s; if (r < 0) r += NAX;
            st = fmaf(z, st, 6.0f * P[swz(r, c)]);
        }
        #pragma unroll
        for (int s = 0; s < 40; ++s) {
            st = fmaf(z, st, 6.0f * P[swz(n0 + s, c)]);
            f[s] = st;
        }
        __syncthreads();
        #pragma unroll
        for (int s = 0; s < 40; ++s) P[swz(n0 + s, c)] = f[s];
        __syncthreads();
        float sm = 0.0f;
        #pragma unroll
        for (int s = KW - 1; s >= 0; --s) {
            int r = n0 + 40 + s; if (r >= NAX) r -= NAX;
            sm = z * (sm - P[swz(r, c)]);
        }
        __syncthreads();
        #pragma unroll
        for (int s = 39; s >= 0; --s) { sm = z * (sm - f[s]); P[swz(n0 + s, c)] = sm; }
        __syncthreads();
    }
    {
        const int rr = c;
        float st = 0.0f;
        #pragma unroll
        for (int s = 0; s < KW; ++s) {
            int cc = n0 - KW + s; if (cc < 0) cc += NAX;
            st = fmaf(z, st, 6.0f * P[swz(rr, cc)]);
        }
        #pragma unroll
        for (int s = 0; s < 40; ++s) {
            st = fmaf(z, st, 6.0f * P[swz(rr, n0 + s)]);
            f[s] = st;
        }
        __syncthreads();
        #pragma unroll
        for (int s = 0; s < 40; ++s) P[swz(rr, n0 + s)] = f[s];
        __syncthreads();
        float sm = 0.0f;
        #pragma unroll
        for (int s = KW - 1; s >= 0; --s) {
            int cc = n0 + 40 + s; if (cc >= NAX) cc -= NAX;
            sm = z * (sm - P[swz(rr, cc)]);
        }
        __syncthreads();
        #pragma unroll
        for (int s = 39; s >= 0; --s) { sm = z * (sm - f[s]); P[swz(rr, n0 + s)] = sm; }
        __syncthreads();
    }
    #pragma unroll
    for (int k = 0; k < 40; ++k) {
        const int r = 4 * k + tq;
        plane[r * NAX + c] = P[swz(r, c)];
    }
}

extern "C" void kernel_launch(void* const* d_in, const int* in_sizes, int n_in,
                              void* d_out, int out_size, void* d_ws, size_t ws_size,
                              hipStream_t stream) {
    (void)in_sizes; (void)n_in; (void)out_size;
    const float* x = (const float*)d_in[0];
    float* out = (float*)d_out;
    float* ws  = (float*)d_ws;

    const size_t need = (size_t)6 * VOL * sizeof(float);   // 98.3 MB intermediate
    if (ws_size >= need) {
        pass_d2 <<<2400, 256, 0, stream>>>(x, ws);     // in -> ws
        slab_d3d4<<<3840, 320, 0, stream>>>(ws, out);  // ws -> out (disjoint)
    } else {
        pass_d2  <<<2400, 256, 0, stream>>>(x, out);
        pass_d3d4<<<960,  640, 0, stream>>>(out);      // validated fallback
    }
}